// Round 4
// baseline (261.068 us; speedup 1.0000x reference)
//
#include <hip/hip_runtime.h>

// AttentionXL (TransformerXL relative attention), MI355X gfx950.
// fp32 I/O. prep (convert3+transpose4 merged) -> gemm3 (kv+q+r batched in one
// dispatch) -> balanced split-j flash -> 3-way combine -> proj GEMM.
// Round 15: 2-phase double-buffered GEMM K-loop. gemm3 was latency-exposed
// (MfmaUtil 14%, VALUBusy 10%, HBM 17%, occupancy 22% -- nothing busy; the
// K-loop had zero overlap: issue DMA -> drain -> compute, 16x per block, at
// only ~2 blocks/CU grid residency). Now: stage K-step t+1 into buf^1 while
// computing buf, one drain barrier per step. LDS 32->64 KB (still 2 blk/CU).

typedef unsigned short u16;
typedef short short8 __attribute__((ext_vector_type(8)));
typedef float f32x4 __attribute__((ext_vector_type(4)));

#define BSZ 4
#define PREV 512

__device__ __forceinline__ float b2f(u16 u) {
  union { unsigned int i; float f; } x; x.i = ((unsigned int)u) << 16; return x.f;
}
__device__ __forceinline__ u16 f2b(float f) {
  union { float f; unsigned int i; } x; x.f = f;
  unsigned int u = x.i;
  return (u16)((u + 0x7fffu + ((u >> 16) & 1u)) >> 16);
}
__device__ __forceinline__ void storeC(u16* C, size_t idx, float v) { C[idx] = f2b(v); }
__device__ __forceinline__ void storeC(float* C, size_t idx, float v) { C[idx] = v; }

// async 16B/lane global->LDS DMA; lds dest = wave-uniform base + lane*16
__device__ __forceinline__ void load_lds16(const u16* g, void* l) {
  __builtin_amdgcn_global_load_lds(
      (const __attribute__((address_space(1))) unsigned int*)g,
      (__attribute__((address_space(3))) unsigned int*)l, 16, 0, 0);
}

// ---------------------------------------------------------------------------
// prep: 3 fp32->bf16 flat converts (blocks 0..3583) + 4 weight transposes
// (blocks 3584..5631) in ONE dispatch.
// ---------------------------------------------------------------------------
__global__ __launch_bounds__(256)
void prep(const float* __restrict__ s0, const float* __restrict__ s1,
          const float* __restrict__ s2, u16* __restrict__ d0,
          u16* __restrict__ d1, u16* __restrict__ d2,
          const float* __restrict__ W0, const float* __restrict__ W1,
          const float* __restrict__ W2, const float* __restrict__ W3,
          u16* __restrict__ T0, u16* __restrict__ T1,
          u16* __restrict__ T2, u16* __restrict__ T3) {
  __shared__ u16 ld[64 * 66];
  const int bxg = blockIdx.x;
  if (bxg < 3584) {
    // --- convert part
    const float* s; u16* d; size_t base;
    if (bxg < 2048)      { s = s0; d = d0; base = (size_t)bxg * 2048; }
    else if (bxg < 3072) { s = s1; d = d1; base = (size_t)(bxg - 2048) * 2048; }
    else                 { s = s2; d = d2; base = (size_t)(bxg - 3072) * 2048; }
    size_t i = base + (size_t)threadIdx.x * 8;
    const f32x4* p = reinterpret_cast<const f32x4*>(s + i);
    f32x4 a = p[0], b = p[1];
    short8 r;
#pragma unroll
    for (int e = 0; e < 4; e++) { r[e] = (short)f2b(a[e]); r[e + 4] = (short)f2b(b[e]); }
    *reinterpret_cast<short8*>(d + i) = r;
    return;
  }
  // --- transpose part (fp32 W[K x N] -> bf16 WT[N x K])
  const int l = bxg - 3584;
  const int z = l >> 9;
  const int rem = l & 511;
  const int bx = rem & 31, by = rem >> 5;
  const float* W; u16* T; int N;
  if (z == 0)      { W = W0; T = T0; N = 2048; }
  else if (z == 1) { W = W1; T = T1; N = 1024; }
  else if (z == 2) { W = W2; T = T2; N = 1024; }
  else             { W = W3; T = T3; N = 1024; }
  const int K = 1024;
  const int n0 = bx * 64, k0 = by * 64;
  if (n0 >= N) return;

  const int tid = threadIdx.x;
#pragma unroll
  for (int rep = 0; rep < 16; rep++) {
    int idx = tid + 256 * rep;
    int kk = idx >> 6, nn = idx & 63;
    ld[kk * 66 + nn] = f2b(W[(size_t)(k0 + kk) * N + n0 + nn]);
  }
  __syncthreads();
#pragma unroll
  for (int rep = 0; rep < 16; rep++) {
    int idx = tid + 256 * rep;
    int nn = idx >> 6, kk = idx & 63;
    T[(size_t)(n0 + nn) * K + k0 + kk] = ld[kk * 66 + nn];
  }
}

// ---------------------------------------------------------------------------
// GEMM core (B^T form): C = A[M,K] @ BT[N,K]^T + bias. 128x128 tile, BK=64,
// 2-phase double-buffered LDS: stage K-step t+1 into buf^1 (async
// global_load_lds DMA) while computing buf; single drain barrier per step.
// at/bt each point to 2 x 8192 shorts.
// MODE 0: row-major C. MODE 1 (kv): Kt2/Vt2 frag-tile order. MODE 2: Rt.
// ---------------------------------------------------------------------------
template <typename OT, int MODE>
__device__ __forceinline__ void gemm_core(
    short* __restrict__ at, short* __restrict__ bt,
    const u16* __restrict__ A, const u16* __restrict__ BT,
    const float* __restrict__ bias, OT* __restrict__ C, u16* __restrict__ C2,
    int N, int K, int bx, int by)
{
  const int tid = threadIdx.x;
  const int lane = tid & 63, w = tid >> 6;
  const int wr = w >> 1, wc = w & 1;
  const int quad = lane >> 4, ml = lane & 15;
  const int row0 = by * 128, col0 = bx * 128;

  // per-lane source row/koff pieces for the DMA staging
  const int srow = lane & 15;          // row within 16-row group
  const int skoff = (lane >> 4) * 8;   // k offset within 32-k half

  f32x4 acc[4][4];
  const f32x4 fzero = {0.f, 0.f, 0.f, 0.f};
#pragma unroll
  for (int i = 0; i < 4; i++)
#pragma unroll
    for (int j = 0; j < 4; j++) acc[i][j] = fzero;

  // stage one 128x64 A-tile + B-tile into buffer `buf` for k-offset k0
  auto stage = [&](int buf, int k0) {
#pragma unroll
    for (int i = 0; i < 4; i++) {
      int c = 4 * w + i;                 // chunk index 0..15
      int mc = c >> 1, kc = c & 1;
      load_lds16(A + (size_t)(row0 + mc * 16 + srow) * K + k0 + kc * 32 + skoff,
                 (void*)(at + buf * 8192 + c * 512));
      load_lds16(BT + (size_t)(col0 + mc * 16 + srow) * K + k0 + kc * 32 + skoff,
                 (void*)(bt + buf * 8192 + c * 512));
    }
  };

  // prologue: fill buf 0, drain, barrier
  stage(0, 0);
  __syncthreads();  // compiler emits vmcnt(0) drain before s_barrier

  int cur = 0;
  for (int k0 = 0; k0 < K; k0 += 64) {
    // issue next tile's DMA into the other buffer (flies under this tile's
    // ds_read + MFMA body instead of being drained back-to-back)
    if (k0 + 64 < K) stage(cur ^ 1, k0 + 64);

    const short* a_ = at + cur * 8192;
    const short* b_ = bt + cur * 8192;
    short8 af[4][2], bf[4][2];
#pragma unroll
    for (int mc = 0; mc < 4; mc++)
#pragma unroll
      for (int kc = 0; kc < 2; kc++)
        af[mc][kc] = *reinterpret_cast<const short8*>(a_ + ((((wr * 4 + mc) * 2 + kc) * 64) + lane) * 8);
#pragma unroll
    for (int nc = 0; nc < 4; nc++)
#pragma unroll
      for (int kc = 0; kc < 2; kc++)
        bf[nc][kc] = *reinterpret_cast<const short8*>(b_ + ((((wc * 4 + nc) * 2 + kc) * 64) + lane) * 8);

#pragma unroll
    for (int mc = 0; mc < 4; mc++)
#pragma unroll
      for (int nc = 0; nc < 4; nc++)
#pragma unroll
        for (int kc = 0; kc < 2; kc++)
          acc[mc][nc] = __builtin_amdgcn_mfma_f32_16x16x32_bf16(af[mc][kc], bf[nc][kc], acc[mc][nc], 0, 0, 0);

    // one barrier per K-step: drains this wave's DMA (vmcnt) and guarantees
    // all waves finished reading buf `cur` before it is restaged next iter.
    __syncthreads();
    cur ^= 1;
  }

#pragma unroll
  for (int nc = 0; nc < 4; nc++) {
    int col = col0 + wc * 64 + nc * 16 + ml;
    float bv = bias[col];
#pragma unroll
    for (int mc = 0; mc < 4; mc++) {
#pragma unroll
      for (int reg = 0; reg < 4; reg++) {
        int row = row0 + wr * 64 + mc * 16 + quad * 4 + reg;
        float val = acc[mc][nc][reg] + bv;
        if constexpr (MODE == 0) {
          storeC(C, (size_t)row * N + col, val);
        } else if constexpr (MODE == 1) {
          int j = row >> 2, bb = row & 3;
          int tile = j >> 6, jl = j & 63;
          if (col < 1024) {  // K half: frag (n=j, k=d)
            int h = col >> 6, d = col & 63;
            int ncj = jl >> 4, nlj = jl & 15, kcd = d >> 5, qdd = (d >> 3) & 3, jjd = d & 7;
            C[((size_t)(bb * 16 + h) * 16 + tile) * 4096 +
              ((ncj * 2 + kcd) * 64 + qdd * 16 + nlj) * 8 + jjd] = f2b(val);
          } else {           // V half: frag (n=d, k=j)
            int c2 = col - 1024;
            int h = c2 >> 6, d = c2 & 63;
            int ncd = d >> 4, nld = d & 15, kcj = jl >> 5, qdj = (jl >> 3) & 3, jjj = jl & 7;
            C2[((size_t)(bb * 16 + h) * 16 + tile) * 4096 +
               ((kcj * 4 + ncd) * 64 + qdj * 16 + nld) * 8 + jjj] = f2b(val);
          }
        } else {             // MODE 2: Rt[h][rel][d]
          int h = col >> 6, d = col & 63;
          C[((size_t)h * 1024 + row) * 64 + d] = f2b(val);
        }
      }
    }
  }
}

// ---------------------------------------------------------------------------
// gemm3: kv (512 blocks) + q (128) + r (64) batched in one 704-block dispatch.
// q/r alone would leave >=half the CUs idle; co-scheduling fills the machine.
// LDS 64 KB (double-buffered) -> 2 blocks/CU residency.
// ---------------------------------------------------------------------------
__global__ __launch_bounds__(256, 2)
void gemm3(const u16* __restrict__ fibf, const u16* __restrict__ WkvT,
           const float* __restrict__ b_kv, u16* __restrict__ Kt2, u16* __restrict__ Vt2,
           const u16* __restrict__ inbf, const u16* __restrict__ WqT,
           const float* __restrict__ b_q, u16* __restrict__ qq,
           const u16* __restrict__ pebf, const u16* __restrict__ WposT,
           const float* __restrict__ b_pos, u16* __restrict__ Rt)
{
  __shared__ __align__(16) short at[16384];
  __shared__ __align__(16) short bt[16384];
  const int id = blockIdx.x;
  if (id < 512) {
    gemm_core<u16, 1>(at, bt, fibf, WkvT, b_kv, Kt2, Vt2, 2048, 1024, id & 15, id >> 4);
  } else if (id < 640) {
    const int l = id - 512;
    gemm_core<u16, 0>(at, bt, inbf, WqT, b_q, qq, (u16*)nullptr, 1024, 1024, l & 7, l >> 3);
  } else {
    const int l = id - 640;
    gemm_core<u16, 2>(at, bt, pebf, WposT, b_pos, Rt, (u16*)nullptr, 1024, 1024, l & 7, l >> 3);
  }
}

__global__ __launch_bounds__(256, 2)
void gemm_proj(const u16* __restrict__ A, const u16* __restrict__ BT,
               const float* __restrict__ bias, float* __restrict__ C)
{
  __shared__ __align__(16) short at[16384];
  __shared__ __align__(16) short bt[16384];
  gemm_core<float, 0>(at, bt, A, BT, bias, C, (u16*)nullptr, 1024, 1024,
                      blockIdx.x, blockIdx.y);
}

// ---------------------------------------------------------------------------
// Balanced split-j fused flash-XL, round-0 proven inner body.
// 20 (it,seg) blocks per (b,h): it 0..3 -> 2 segments, it 4..7 -> 3 segments;
// max 6 j-tiles per block; 1280 blocks, LDS-limited 6 blocks/CU residency.
// ---------------------------------------------------------------------------
__global__ __launch_bounds__(256, 4)
void flash_xl(const u16* __restrict__ q, const u16* __restrict__ Kt2,
              const u16* __restrict__ Vt2, const u16* __restrict__ Rt,
              const float* __restrict__ u, const float* __restrict__ v,
              float* __restrict__ po, float* __restrict__ pm,
              float* __restrict__ pl)
{
  __shared__ __align__(16) short kb[4096];
  __shared__ __align__(16) short vb[4096];
  __shared__ __align__(16) short pt[4][1024];

  const int tid = threadIdx.x, lane = tid & 63, w = tid >> 6;
  const int quad = lane >> 4, ml = lane & 15;
  const int x = blockIdx.x;
  int it, s, nseg;
  if (x < 12) { int g = x / 3; it = 7 - g; s = x - g * 3; nseg = 3; }
  else        { int y = x - 12; it = 3 - (y >> 1); s = y & 1; nseg = 2; }
  const int nt = it + 9;                       // total tiles covering j <= i0+63+512
  const int qn = (nseg == 3) ? (nt / 3) : (nt >> 1);
  const int rn = nt - qn * nseg;
  const int ts = s * qn + (s < rn ? s : rn);
  const int te = ts + qn + (s < rn ? 1 : 0);   // te - ts <= 6

  const int b = blockIdx.y, h = blockIdx.z;
  const int bh = b * 16 + h;
  const int i0 = it * 64, ig0 = i0 + w * 16;

  const u16* Kbase = Kt2 + ((size_t)(b * 16 + h) * 16) * 4096;
  const u16* Vbase = Vt2 + ((size_t)(b * 16 + h) * 16) * 4096;
  const u16* Rp = Rt + (size_t)h * 65536;

  // Q fragments, pre-scaled by 1/8: rows ig0+ml, k = kc*32+quad*8+e
  short8 qu[2], qvf[2];
  {
    int ig = ig0 + ml;
#pragma unroll
    for (int kc = 0; kc < 2; kc++) {
      int dbase = kc * 32 + quad * 8;
      short8 qq = *reinterpret_cast<const short8*>(q + ((size_t)ig * BSZ + b) * 1024 + h * 64 + dbase);
      const f32x4* up = reinterpret_cast<const f32x4*>(u + h * 64 + dbase);
      const f32x4* vp = reinterpret_cast<const f32x4*>(v + h * 64 + dbase);
      f32x4 u0 = up[0], u1 = up[1], v0 = vp[0], v1 = vp[1];
#pragma unroll
      for (int e = 0; e < 8; e++) {
        float qf = b2f((u16)qq[e]);
        float uu = (e < 4) ? u0[e] : u1[e - 4];
        float vv = (e < 4) ? v0[e] : v1[e - 4];
        qu[kc][e]  = (short)f2b((qf + uu) * 0.125f);
        qvf[kc][e] = (short)f2b((qf + vv) * 0.125f);
      }
    }
  }

  const f32x4 fzero = {0.f, 0.f, 0.f, 0.f};
  f32x4 o_acc[4];
#pragma unroll
  for (int i = 0; i < 4; i++) o_acc[i] = fzero;
  float m_run[4], l_run[4];
#pragma unroll
  for (int i = 0; i < 4; i++) { m_run[i] = -1e30f; l_run[i] = 0.f; }

  // ---- prologue: prefetch tile ts's identity chunks into registers
  short8 pk0, pk1, pv0, pv1;
  {
    const u16* kg = Kbase + (size_t)ts * 4096;
    const u16* vg = Vbase + (size_t)ts * 4096;
    pk0 = *reinterpret_cast<const short8*>(kg + tid * 8);
    pk1 = *reinterpret_cast<const short8*>(kg + 2048 + tid * 8);
    pv0 = *reinterpret_cast<const short8*>(vg + tid * 8);
    pv1 = *reinterpret_cast<const short8*>(vg + 2048 + tid * 8);
  }

  for (int t = ts; t < te; t++) {
    const int j0 = t * 64;
    __syncthreads();  // previous tile fully consumed
    *reinterpret_cast<short8*>(kb + tid * 8) = pk0;
    *reinterpret_cast<short8*>(kb + 2048 + tid * 8) = pk1;
    *reinterpret_cast<short8*>(vb + tid * 8) = pv0;
    *reinterpret_cast<short8*>(vb + 2048 + tid * 8) = pv1;
    __syncthreads();  // staging visible

    // ---- issue next tile's prefetch (latency hidden behind this tile's body)
    if (t + 1 < te) {
      const u16* kg = Kbase + (size_t)(t + 1) * 4096;
      const u16* vg = Vbase + (size_t)(t + 1) * 4096;
      pk0 = *reinterpret_cast<const short8*>(kg + tid * 8);
      pk1 = *reinterpret_cast<const short8*>(kg + 2048 + tid * 8);
      pv0 = *reinterpret_cast<const short8*>(vg + tid * 8);
      pv1 = *reinterpret_cast<const short8*>(vg + 2048 + tid * 8);
    }

    // ---- content scores: K B-frags from LDS
    f32x4 sc[4];
#pragma unroll
    for (int nc = 0; nc < 4; nc++) {
      sc[nc] = fzero;
#pragma unroll
      for (int kc = 0; kc < 2; kc++) {
        short8 kf = *reinterpret_cast<const short8*>(kb + ((nc * 2 + kc) * 64 + lane) * 8);
        sc[nc] = __builtin_amdgcn_mfma_f32_16x16x32_bf16(qu[kc], kf, sc[nc], 0, 0, 0);
      }
    }
    // ---- position strip: R B-frags direct from global (dense 1KB windows)
    const int relstart = j0 - ig0 + 496;  // >= 0
    f32x4 p2[5];
#pragma unroll
    for (int c = 0; c < 5; c++) {
      p2[c] = fzero;
      int rel = relstart + c * 16 + ml;
      if (rel > 1023) rel = 1023;  // clamped rows are masked below
      const u16* rp = Rp + (size_t)rel * 64 + quad * 8;
#pragma unroll
      for (int kc = 0; kc < 2; kc++) {
        short8 rf = *reinterpret_cast<const short8*>(rp + kc * 32);
        p2[c] = __builtin_amdgcn_mfma_f32_16x16x32_bf16(qvf[kc], rf, p2[c], 0, 0, 0);
      }
    }

    // ---- rel-shift gather (quad-local shuffles) + mask + online softmax
    const bool anymask = (j0 + 63) > (ig0 + PREV);
    float pv_[4][4];
    float tmax[4] = {-1e30f, -1e30f, -1e30f, -1e30f};
#pragma unroll
    for (int reg = 0; reg < 4; reg++) {
      int rowl = quad * 4 + reg;
      int src = quad * 16 + ((ml - rowl - 1) & 15);
      bool hi = ml > rowl;
      float sh[5];
#pragma unroll
      for (int c = 0; c < 5; c++) sh[c] = __shfl(p2[c][reg], src, 64);
#pragma unroll
      for (int nc = 0; nc < 4; nc++) {
        float sv = sc[nc][reg] + (hi ? sh[nc + 1] : sh[nc]);
        if (anymask) {
          int jg = j0 + nc * 16 + ml;
          if (jg > ig0 + rowl + PREV) sv = -1e30f;
        }
        pv_[nc][reg] = sv;
        tmax[reg] = fmaxf(tmax[reg], sv);
      }
    }
#pragma unroll
    for (int reg = 0; reg < 4; reg++) {
      float tm = tmax[reg];
#pragma unroll
      for (int off = 1; off < 16; off <<= 1) tm = fmaxf(tm, __shfl_xor(tm, off, 64));
      float mnew = fmaxf(m_run[reg], tm);
      float alpha = __expf(m_run[reg] - mnew);
      float rs = 0.f;
#pragma unroll
      for (int nc = 0; nc < 4; nc++) {
        float p = __expf(pv_[nc][reg] - mnew);
        pv_[nc][reg] = p;
        rs += p;
      }
#pragma unroll
      for (int off = 1; off < 16; off <<= 1) rs += __shfl_xor(rs, off, 64);
      l_run[reg] = l_run[reg] * alpha + rs;
      m_run[reg] = mnew;
#pragma unroll
      for (int nc = 0; nc < 4; nc++) o_acc[nc][reg] *= alpha;
    }

    // ---- P (C layout) -> bf16 A-frag via per-wave LDS (wave-order safe)
#pragma unroll
    for (int nc = 0; nc < 4; nc++) {
      int jl = nc * 16 + ml;
      int kc = nc >> 1, qdj = (jl >> 3) & 3, jj = ml & 7;
#pragma unroll
      for (int reg = 0; reg < 4; reg++) {
        int rowl = quad * 4 + reg;
        pt[w][(kc * 64 + qdj * 16 + rowl) * 8 + jj] = (short)f2b(pv_[nc][reg]);
      }
    }
    short8 pf[2];
    pf[0] = *reinterpret_cast<const short8*>(pt[w] + (0 * 64 + lane) * 8);
    pf[1] = *reinterpret_cast<const short8*>(pt[w] + (1 * 64 + lane) * 8);

    // ---- PV: V B-frags from LDS (k = kc*32 + quad*8 + e)
#pragma unroll
    for (int ncd = 0; ncd < 4; ncd++)
#pragma unroll
      for (int kc = 0; kc < 2; kc++) {
        short8 vf = *reinterpret_cast<const short8*>(vb + ((kc * 4 + ncd) * 64 + lane) * 8);
        o_acc[ncd] = __builtin_amdgcn_mfma_f32_16x16x32_bf16(pf[kc], vf, o_acc[ncd], 0, 0, 0);
      }
  }

  // ---- write unnormalized partials.
  // slots 0/1: ridx = (s*512+ig)*64 + b*16 + h   (rows 0..65535)
  // slot  2  : ridx = 65536 + (ig-256)*64 + b*16 + h  (only it>=4 -> ig>=256)
#pragma unroll
  for (int reg = 0; reg < 4; reg++) {
    int ig = ig0 + quad * 4 + reg;
    size_t ridx = (s < 2) ? ((size_t)(s * 512 + ig) * 64 + bh)
                          : ((size_t)65536 + (size_t)(ig - 256) * 64 + bh);
    if (ml == 0) { pm[ridx] = m_run[reg]; pl[ridx] = l_run[reg]; }
#pragma unroll
    for (int ncd = 0; ncd < 4; ncd++)
      po[ridx * 64 + ncd * 16 + ml] = o_acc[ncd][reg];
  }
}

// ---------------------------------------------------------------------------
// Merge the (2 or 3) j-segments. m is in natural-log units -> __expf weights.
// ---------------------------------------------------------------------------
__global__ __launch_bounds__(256)
void combine(const float* __restrict__ po, const float* __restrict__ pm,
             const float* __restrict__ pl, u16* __restrict__ av) {
  int idx = blockIdx.x * 256 + threadIdx.x;  // 2,097,152 total
  int d = idx & 63;
  int r0 = idx >> 6;                         // ig*64 + b*16 + h
  int ig = r0 >> 6;
  float m1 = pm[r0], m2 = pm[32768 + r0];
  float l1 = pl[r0], l2 = pl[32768 + r0];
  float o1 = po[(size_t)r0 * 64 + d];
  float o2 = po[((size_t)32768 + r0) * 64 + d];
  float m = fmaxf(m1, m2);
  const bool h3 = ig >= 256;                 // slot 2 exists only for it>=4
  int r2 = r0 + 49152;                       // 65536 + (ig-256)*64+bh = r0+49152
  float m3 = -1e30f, l3 = 0.f, o3 = 0.f;
  if (h3) { m3 = pm[r2]; l3 = pl[r2]; o3 = po[(size_t)r2 * 64 + d]; m = fmaxf(m, m3); }
  float a1 = __expf(m1 - m), a2 = __expf(m2 - m);
  float l = l1 * a1 + l2 * a2;
  float o = o1 * a1 + o2 * a2;
  if (h3) { float a3 = __expf(m3 - m); l += l3 * a3; o += o3 * a3; }
  av[(size_t)r0 * 64 + d] = f2b(o / l);
}

// ---------------------------------------------------------------------------
extern "C" void kernel_launch(void* const* d_in, const int* in_sizes, int n_in,
                              void* d_out, int out_size, void* d_ws, size_t ws_size,
                              hipStream_t stream) {
  (void)in_sizes; (void)n_in; (void)out_size; (void)ws_size;

  const float* inputs  = (const float*)d_in[0];   // (512,4,1024)
  const float* pos_emb = (const float*)d_in[1];   // (1024,1,1024)
  const float* full_in = (const float*)d_in[2];   // (1024,4,1024)
  const float* u       = (const float*)d_in[3];   // (16,64)
  const float* v       = (const float*)d_in[4];   // (16,64)
  const float* W_kv    = (const float*)d_in[5];   // (1024,2048)
  const float* b_kv    = (const float*)d_in[6];   // (2048,)
  const float* W_q     = (const float*)d_in[7];   // (1024,1024)
  const float* b_q     = (const float*)d_in[8];
  const float* W_pos   = (const float*)d_in[9];   // (1024,1024)
  const float* b_pos   = (const float*)d_in[10];
  const float* W_proj  = (const float*)d_in[11];  // (1024,1024)
  const float* b_proj  = (const float*)d_in[12];
  // d_in[13] = mask (bool) — recomputed analytically (j > i + 512)
  float* out = (float*)d_out;

  char* ws = (char*)d_ws;
  u16* Kt2   = (u16*)(ws);                  //  8 MB: [4][16][16 tiles][4096] frag order
  u16* Vt2   = (u16*)(ws + ( 8u << 20));    //  8 MB: same shape, V frag order
  u16* qq    = (u16*)(ws + (16u << 20));    //  4 MB: 2048x1024
  u16* Rt    = (u16*)(ws + (20u << 20));    //  2 MB: [16 h][1024 rel][64 d]
  u16* av    = (u16*)(ws + (22u << 20));    //  4 MB: 2048x1024
  u16* WkvT  = (u16*)(ws + (26u << 20));    //  4 MB
  u16* WqT   = (u16*)(ws + (30u << 20));    //  2 MB
  u16* WposT = (u16*)(ws + (32u << 20));    //  2 MB
  u16* WprojT= (u16*)(ws + (34u << 20));    //  2 MB
  u16* fibf  = (u16*)(ws + (36u << 20));    //  8 MB (dead after gemm3)
  u16* inbf  = (u16*)(ws + (44u << 20));    //  4 MB (dead after gemm3)
  u16* pebf  = (u16*)(ws + (48u << 20));    //  2 MB (dead after gemm3)
  float* po  = (float*)(ws + (36u << 20));  // 20 MB partial O (slots 0/1/2; overlays the above)
  float* pm  = (float*)(ws + (56u << 20));  // 320 KB partial m (81920 floats)
  float* pl  = (float*)(ws + (57u << 20));  // 320 KB partial l

  // --- precompute (converts + weight transposes, one dispatch)
  hipLaunchKernelGGL(prep, dim3(5632), dim3(256), 0, stream,
                     full_in, inputs, pos_emb, fibf, inbf, pebf,
                     W_kv, W_q, W_pos, W_proj, WkvT, WqT, WposT, WprojT);

  // --- kv + q + r GEMMs, one dispatch (704 blocks)
  hipLaunchKernelGGL(gemm3, dim3(704), dim3(256), 0, stream,
                     fibf, WkvT, b_kv, Kt2, Vt2,
                     inbf, WqT, b_q, qq,
                     pebf, WposT, b_pos, Rt);

  // --- balanced split-j fused attention + 3-way combine
  hipLaunchKernelGGL(flash_xl, dim3(20, 4, 16), dim3(256), 0, stream,
                     qq, Kt2, Vt2, Rt, u, v, po, pm, pl);
  hipLaunchKernelGGL(combine, dim3(8192), dim3(256), 0, stream, po, pm, pl, av);

  // --- output projection
  hipLaunchKernelGGL(gemm_proj, dim3(8, 16), dim3(256), 0, stream,
                     av, WprojT, b_proj, out);
}

// Round 5
// 231.467 us; speedup vs baseline: 1.1279x; 1.1279x over previous
//
#include <hip/hip_runtime.h>

// AttentionXL (TransformerXL relative attention), MI355X gfx950.
// fp32 I/O. prep (convert+transpose, writes PACKED operands) -> gemm3
// (kv+q+r batched) -> balanced split-j flash -> 3-way combine (writes packed
// av) -> proj GEMM.
// Round 16: coalesced GEMM staging via packed operand layout. The old
// staging DMA read 64 lanes x 16B at 2KB stride (frag-order gather straight
// from row-major A/BT) = 64 scattered transactions/inst and 2.8x FETCH
// overfetch (61.8 MB vs 22 ideal). Producers (prep, combine) now emit
// operands pre-packed in 16x32 MFMA frag chunks; every global_load_lds is a
// contiguous 1KB; ds_read pattern unchanged (0 conflicts). Round-4's dbuf
// reverted (null-to-negative: vmcnt(0)-at-barrier drains the prefetch, and
// 64KB LDS halved residency).

typedef unsigned short u16;
typedef short short8 __attribute__((ext_vector_type(8)));
typedef float f32x4 __attribute__((ext_vector_type(4)));

#define BSZ 4
#define PREV 512

__device__ __forceinline__ float b2f(u16 u) {
  union { unsigned int i; float f; } x; x.i = ((unsigned int)u) << 16; return x.f;
}
__device__ __forceinline__ u16 f2b(float f) {
  union { float f; unsigned int i; } x; x.f = f;
  unsigned int u = x.i;
  return (u16)((u + 0x7fffu + ((u >> 16) & 1u)) >> 16);
}
__device__ __forceinline__ void storeC(u16* C, size_t idx, float v) { C[idx] = f2b(v); }
__device__ __forceinline__ void storeC(float* C, size_t idx, float v) { C[idx] = v; }

// async 16B/lane global->LDS DMA; lds dest = wave-uniform base + lane*16
__device__ __forceinline__ void load_lds16(const u16* g, void* l) {
  __builtin_amdgcn_global_load_lds(
      (const __attribute__((address_space(1))) unsigned int*)g,
      (__attribute__((address_space(3))) unsigned int*)l, 16, 0, 0);
}

// Packed operand layout: matrix [R][K] tiled into 16x32 chunks of 512 u16.
// chunk = (row/16)*(K/32) + k/32; within-chunk = frag order
// [quad=(k>>3)&3][ml=row&15][e=k&7] -> a wave's lane*16B linear read of one
// chunk IS the MFMA A/B fragment layout. k must be 8-aligned here.
__device__ __forceinline__ size_t pidx8(int row, int k, int K32) {
  return (((size_t)((row >> 4) * K32 + (k >> 5))) << 9) +
         (((k >> 3) & 3) << 7) + ((row & 15) << 3);
}

// ---------------------------------------------------------------------------
// prep: 3 fp32->bf16 converts into PACKED layout (blocks 0..3583) + 4 weight
// transposes (fp32 W[K x N] -> packed bf16 WT) (blocks 3584..5631).
// ---------------------------------------------------------------------------
__global__ __launch_bounds__(256)
void prep(const float* __restrict__ s0, const float* __restrict__ s1,
          const float* __restrict__ s2, u16* __restrict__ d0,
          u16* __restrict__ d1, u16* __restrict__ d2,
          const float* __restrict__ W0, const float* __restrict__ W1,
          const float* __restrict__ W2, const float* __restrict__ W3,
          u16* __restrict__ T0, u16* __restrict__ T1,
          u16* __restrict__ T2, u16* __restrict__ T3) {
  __shared__ u16 ld[64 * 66];
  const int bxg = blockIdx.x;
  if (bxg < 3584) {
    // --- convert part: src row-major [R][1024], dst packed
    const float* s; u16* d; size_t base;
    if (bxg < 2048)      { s = s0; d = d0; base = (size_t)bxg * 2048; }
    else if (bxg < 3072) { s = s1; d = d1; base = (size_t)(bxg - 2048) * 2048; }
    else                 { s = s2; d = d2; base = (size_t)(bxg - 3072) * 2048; }
    size_t i = base + (size_t)threadIdx.x * 8;
    const f32x4* p = reinterpret_cast<const f32x4*>(s + i);
    f32x4 a = p[0], b = p[1];
    short8 r;
#pragma unroll
    for (int e = 0; e < 4; e++) { r[e] = (short)f2b(a[e]); r[e + 4] = (short)f2b(b[e]); }
    int row = (int)(i >> 10), k = (int)(i & 1023);
    *reinterpret_cast<short8*>(d + pidx8(row, k, 32)) = r;
    return;
  }
  // --- transpose part: W[K x N] -> packed WT (rows = n, cols = k, K=1024)
  const int l = bxg - 3584;
  const int z = l >> 9;
  const int rem = l & 511;
  const int bx = rem & 31, by = rem >> 5;
  const float* W; u16* T; int N;
  if (z == 0)      { W = W0; T = T0; N = 2048; }
  else if (z == 1) { W = W1; T = T1; N = 1024; }
  else if (z == 2) { W = W2; T = T2; N = 1024; }
  else             { W = W3; T = T3; N = 1024; }
  const int n0 = bx * 64, k0 = by * 64;
  if (n0 >= N) return;

  const int tid = threadIdx.x;
#pragma unroll
  for (int rep = 0; rep < 16; rep++) {
    int idx = tid + 256 * rep;
    int kk = idx >> 6, nn = idx & 63;
    ld[kk * 66 + nn] = f2b(W[(size_t)(k0 + kk) * N + n0 + nn]);
  }
  __syncthreads();
#pragma unroll
  for (int rep = 0; rep < 2; rep++) {
    int idx = tid + 256 * rep;           // 0..511
    int nn = idx >> 3, k8 = (idx & 7) * 8;
    short8 r;
#pragma unroll
    for (int e = 0; e < 8; e++) r[e] = (short)ld[(k8 + e) * 66 + nn];
    *reinterpret_cast<short8*>(T + pidx8(n0 + nn, k0 + k8, 32)) = r;
  }
}

// ---------------------------------------------------------------------------
// GEMM core: C = A @ BT^T + bias, A/BT in PACKED chunk layout. 128x128 tile,
// BK=64, single-buffer. Staging = 8 x contiguous-1KB global_load_lds per
// wave per K-step; ds_read frag reads are lane-linear (0 bank conflicts).
// MODE 0: row-major C. MODE 1 (kv): Kt2/Vt2 frag-tile order. MODE 2: Rt.
// ---------------------------------------------------------------------------
template <typename OT, int MODE>
__device__ __forceinline__ void gemm_core(
    short* __restrict__ at, short* __restrict__ bt,
    const u16* __restrict__ A, const u16* __restrict__ BT,
    const float* __restrict__ bias, OT* __restrict__ C, u16* __restrict__ C2,
    int N, int K, int bx, int by)
{
  const int tid = threadIdx.x;
  const int lane = tid & 63, w = tid >> 6;
  const int wr = w >> 1, wc = w & 1;
  const int quad = lane >> 4, ml = lane & 15;
  const int row0 = by * 128, col0 = bx * 128;
  const int K32 = K >> 5;

  f32x4 acc[4][4];
  const f32x4 fzero = {0.f, 0.f, 0.f, 0.f};
#pragma unroll
  for (int i = 0; i < 4; i++)
#pragma unroll
    for (int j = 0; j < 4; j++) acc[i][j] = fzero;

  for (int k0 = 0; k0 < K; k0 += 64) {
    __syncthreads();  // previous tile fully consumed
#pragma unroll
    for (int i = 0; i < 4; i++) {
      int c = 4 * w + i;                 // chunk index 0..15
      int mc = c >> 1, kc = c & 1;
      size_t ca = ((size_t)(((row0 >> 4) + mc) * K32 + (k0 >> 5) + kc)) << 9;
      size_t cb = ((size_t)(((col0 >> 4) + mc) * K32 + (k0 >> 5) + kc)) << 9;
      load_lds16(A + ca + lane * 8, (void*)(at + c * 512));
      load_lds16(BT + cb + lane * 8, (void*)(bt + c * 512));
    }
    __syncthreads();  // drains vmcnt; staging visible

    short8 af[4][2], bf[4][2];
#pragma unroll
    for (int mc = 0; mc < 4; mc++)
#pragma unroll
      for (int kc = 0; kc < 2; kc++)
        af[mc][kc] = *reinterpret_cast<const short8*>(at + ((((wr * 4 + mc) * 2 + kc) * 64) + lane) * 8);
#pragma unroll
    for (int nc = 0; nc < 4; nc++)
#pragma unroll
      for (int kc = 0; kc < 2; kc++)
        bf[nc][kc] = *reinterpret_cast<const short8*>(bt + ((((wc * 4 + nc) * 2 + kc) * 64) + lane) * 8);

#pragma unroll
    for (int mc = 0; mc < 4; mc++)
#pragma unroll
      for (int nc = 0; nc < 4; nc++)
#pragma unroll
        for (int kc = 0; kc < 2; kc++)
          acc[mc][nc] = __builtin_amdgcn_mfma_f32_16x16x32_bf16(af[mc][kc], bf[nc][kc], acc[mc][nc], 0, 0, 0);
  }

#pragma unroll
  for (int nc = 0; nc < 4; nc++) {
    int col = col0 + wc * 64 + nc * 16 + ml;
    float bv = bias[col];
#pragma unroll
    for (int mc = 0; mc < 4; mc++) {
#pragma unroll
      for (int reg = 0; reg < 4; reg++) {
        int row = row0 + wr * 64 + mc * 16 + quad * 4 + reg;
        float val = acc[mc][nc][reg] + bv;
        if constexpr (MODE == 0) {
          storeC(C, (size_t)row * N + col, val);
        } else if constexpr (MODE == 1) {
          int j = row >> 2, bb = row & 3;
          int tile = j >> 6, jl = j & 63;
          if (col < 1024) {  // K half: frag (n=j, k=d)
            int h = col >> 6, d = col & 63;
            int ncj = jl >> 4, nlj = jl & 15, kcd = d >> 5, qdd = (d >> 3) & 3, jjd = d & 7;
            C[((size_t)(bb * 16 + h) * 16 + tile) * 4096 +
              ((ncj * 2 + kcd) * 64 + qdd * 16 + nlj) * 8 + jjd] = f2b(val);
          } else {           // V half: frag (n=d, k=j)
            int c2 = col - 1024;
            int h = c2 >> 6, d = c2 & 63;
            int ncd = d >> 4, nld = d & 15, kcj = jl >> 5, qdj = (jl >> 3) & 3, jjj = jl & 7;
            C2[((size_t)(bb * 16 + h) * 16 + tile) * 4096 +
               ((kcj * 4 + ncd) * 64 + qdj * 16 + nld) * 8 + jjj] = f2b(val);
          }
        } else {             // MODE 2: Rt[h][rel][d]
          int h = col >> 6, d = col & 63;
          C[((size_t)h * 1024 + row) * 64 + d] = f2b(val);
        }
      }
    }
  }
}

// ---------------------------------------------------------------------------
// gemm3: kv (512 blocks) + q (128) + r (64) batched in one 704-block dispatch.
// ---------------------------------------------------------------------------
__global__ __launch_bounds__(256, 2)
void gemm3(const u16* __restrict__ fibf, const u16* __restrict__ WkvT,
           const float* __restrict__ b_kv, u16* __restrict__ Kt2, u16* __restrict__ Vt2,
           const u16* __restrict__ inbf, const u16* __restrict__ WqT,
           const float* __restrict__ b_q, u16* __restrict__ qq,
           const u16* __restrict__ pebf, const u16* __restrict__ WposT,
           const float* __restrict__ b_pos, u16* __restrict__ Rt)
{
  __shared__ __align__(16) short at[8192];
  __shared__ __align__(16) short bt[8192];
  const int id = blockIdx.x;
  if (id < 512) {
    gemm_core<u16, 1>(at, bt, fibf, WkvT, b_kv, Kt2, Vt2, 2048, 1024, id & 15, id >> 4);
  } else if (id < 640) {
    const int l = id - 512;
    gemm_core<u16, 0>(at, bt, inbf, WqT, b_q, qq, (u16*)nullptr, 1024, 1024, l & 7, l >> 3);
  } else {
    const int l = id - 640;
    gemm_core<u16, 2>(at, bt, pebf, WposT, b_pos, Rt, (u16*)nullptr, 1024, 1024, l & 7, l >> 3);
  }
}

__global__ __launch_bounds__(256, 2)
void gemm_proj(const u16* __restrict__ A, const u16* __restrict__ BT,
               const float* __restrict__ bias, float* __restrict__ C)
{
  __shared__ __align__(16) short at[8192];
  __shared__ __align__(16) short bt[8192];
  gemm_core<float, 0>(at, bt, A, BT, bias, C, (u16*)nullptr, 1024, 1024,
                      blockIdx.x, blockIdx.y);
}

// ---------------------------------------------------------------------------
// Balanced split-j fused flash-XL, round-0 proven inner body.
// 20 (it,seg) blocks per (b,h): it 0..3 -> 2 segments, it 4..7 -> 3 segments;
// max 6 j-tiles per block; 1280 blocks, LDS-limited 6 blocks/CU residency.
// ---------------------------------------------------------------------------
__global__ __launch_bounds__(256, 4)
void flash_xl(const u16* __restrict__ q, const u16* __restrict__ Kt2,
              const u16* __restrict__ Vt2, const u16* __restrict__ Rt,
              const float* __restrict__ u, const float* __restrict__ v,
              float* __restrict__ po, float* __restrict__ pm,
              float* __restrict__ pl)
{
  __shared__ __align__(16) short kb[4096];
  __shared__ __align__(16) short vb[4096];
  __shared__ __align__(16) short pt[4][1024];

  const int tid = threadIdx.x, lane = tid & 63, w = tid >> 6;
  const int quad = lane >> 4, ml = lane & 15;
  const int x = blockIdx.x;
  int it, s, nseg;
  if (x < 12) { int g = x / 3; it = 7 - g; s = x - g * 3; nseg = 3; }
  else        { int y = x - 12; it = 3 - (y >> 1); s = y & 1; nseg = 2; }
  const int nt = it + 9;                       // total tiles covering j <= i0+63+512
  const int qn = (nseg == 3) ? (nt / 3) : (nt >> 1);
  const int rn = nt - qn * nseg;
  const int ts = s * qn + (s < rn ? s : rn);
  const int te = ts + qn + (s < rn ? 1 : 0);   // te - ts <= 6

  const int b = blockIdx.y, h = blockIdx.z;
  const int bh = b * 16 + h;
  const int i0 = it * 64, ig0 = i0 + w * 16;

  const u16* Kbase = Kt2 + ((size_t)(b * 16 + h) * 16) * 4096;
  const u16* Vbase = Vt2 + ((size_t)(b * 16 + h) * 16) * 4096;
  const u16* Rp = Rt + (size_t)h * 65536;

  // Q fragments, pre-scaled by 1/8: rows ig0+ml, k = kc*32+quad*8+e
  short8 qu[2], qvf[2];
  {
    int ig = ig0 + ml;
#pragma unroll
    for (int kc = 0; kc < 2; kc++) {
      int dbase = kc * 32 + quad * 8;
      short8 qq = *reinterpret_cast<const short8*>(q + ((size_t)ig * BSZ + b) * 1024 + h * 64 + dbase);
      const f32x4* up = reinterpret_cast<const f32x4*>(u + h * 64 + dbase);
      const f32x4* vp = reinterpret_cast<const f32x4*>(v + h * 64 + dbase);
      f32x4 u0 = up[0], u1 = up[1], v0 = vp[0], v1 = vp[1];
#pragma unroll
      for (int e = 0; e < 8; e++) {
        float qf = b2f((u16)qq[e]);
        float uu = (e < 4) ? u0[e] : u1[e - 4];
        float vv = (e < 4) ? v0[e] : v1[e - 4];
        qu[kc][e]  = (short)f2b((qf + uu) * 0.125f);
        qvf[kc][e] = (short)f2b((qf + vv) * 0.125f);
      }
    }
  }

  const f32x4 fzero = {0.f, 0.f, 0.f, 0.f};
  f32x4 o_acc[4];
#pragma unroll
  for (int i = 0; i < 4; i++) o_acc[i] = fzero;
  float m_run[4], l_run[4];
#pragma unroll
  for (int i = 0; i < 4; i++) { m_run[i] = -1e30f; l_run[i] = 0.f; }

  // ---- prologue: prefetch tile ts's identity chunks into registers
  short8 pk0, pk1, pv0, pv1;
  {
    const u16* kg = Kbase + (size_t)ts * 4096;
    const u16* vg = Vbase + (size_t)ts * 4096;
    pk0 = *reinterpret_cast<const short8*>(kg + tid * 8);
    pk1 = *reinterpret_cast<const short8*>(kg + 2048 + tid * 8);
    pv0 = *reinterpret_cast<const short8*>(vg + tid * 8);
    pv1 = *reinterpret_cast<const short8*>(vg + 2048 + tid * 8);
  }

  for (int t = ts; t < te; t++) {
    const int j0 = t * 64;
    __syncthreads();  // previous tile fully consumed
    *reinterpret_cast<short8*>(kb + tid * 8) = pk0;
    *reinterpret_cast<short8*>(kb + 2048 + tid * 8) = pk1;
    *reinterpret_cast<short8*>(vb + tid * 8) = pv0;
    *reinterpret_cast<short8*>(vb + 2048 + tid * 8) = pv1;
    __syncthreads();  // staging visible

    // ---- issue next tile's prefetch (latency hidden behind this tile's body)
    if (t + 1 < te) {
      const u16* kg = Kbase + (size_t)(t + 1) * 4096;
      const u16* vg = Vbase + (size_t)(t + 1) * 4096;
      pk0 = *reinterpret_cast<const short8*>(kg + tid * 8);
      pk1 = *reinterpret_cast<const short8*>(kg + 2048 + tid * 8);
      pv0 = *reinterpret_cast<const short8*>(vg + tid * 8);
      pv1 = *reinterpret_cast<const short8*>(vg + 2048 + tid * 8);
    }

    // ---- content scores: K B-frags from LDS
    f32x4 sc[4];
#pragma unroll
    for (int nc = 0; nc < 4; nc++) {
      sc[nc] = fzero;
#pragma unroll
      for (int kc = 0; kc < 2; kc++) {
        short8 kf = *reinterpret_cast<const short8*>(kb + ((nc * 2 + kc) * 64 + lane) * 8);
        sc[nc] = __builtin_amdgcn_mfma_f32_16x16x32_bf16(qu[kc], kf, sc[nc], 0, 0, 0);
      }
    }
    // ---- position strip: R B-frags direct from global (dense 1KB windows)
    const int relstart = j0 - ig0 + 496;  // >= 0
    f32x4 p2[5];
#pragma unroll
    for (int c = 0; c < 5; c++) {
      p2[c] = fzero;
      int rel = relstart + c * 16 + ml;
      if (rel > 1023) rel = 1023;  // clamped rows are masked below
      const u16* rp = Rp + (size_t)rel * 64 + quad * 8;
#pragma unroll
      for (int kc = 0; kc < 2; kc++) {
        short8 rf = *reinterpret_cast<const short8*>(rp + kc * 32);
        p2[c] = __builtin_amdgcn_mfma_f32_16x16x32_bf16(qvf[kc], rf, p2[c], 0, 0, 0);
      }
    }

    // ---- rel-shift gather (quad-local shuffles) + mask + online softmax
    const bool anymask = (j0 + 63) > (ig0 + PREV);
    float pv_[4][4];
    float tmax[4] = {-1e30f, -1e30f, -1e30f, -1e30f};
#pragma unroll
    for (int reg = 0; reg < 4; reg++) {
      int rowl = quad * 4 + reg;
      int src = quad * 16 + ((ml - rowl - 1) & 15);
      bool hi = ml > rowl;
      float sh[5];
#pragma unroll
      for (int c = 0; c < 5; c++) sh[c] = __shfl(p2[c][reg], src, 64);
#pragma unroll
      for (int nc = 0; nc < 4; nc++) {
        float sv = sc[nc][reg] + (hi ? sh[nc + 1] : sh[nc]);
        if (anymask) {
          int jg = j0 + nc * 16 + ml;
          if (jg > ig0 + rowl + PREV) sv = -1e30f;
        }
        pv_[nc][reg] = sv;
        tmax[reg] = fmaxf(tmax[reg], sv);
      }
    }
#pragma unroll
    for (int reg = 0; reg < 4; reg++) {
      float tm = tmax[reg];
#pragma unroll
      for (int off = 1; off < 16; off <<= 1) tm = fmaxf(tm, __shfl_xor(tm, off, 64));
      float mnew = fmaxf(m_run[reg], tm);
      float alpha = __expf(m_run[reg] - mnew);
      float rs = 0.f;
#pragma unroll
      for (int nc = 0; nc < 4; nc++) {
        float p = __expf(pv_[nc][reg] - mnew);
        pv_[nc][reg] = p;
        rs += p;
      }
#pragma unroll
      for (int off = 1; off < 16; off <<= 1) rs += __shfl_xor(rs, off, 64);
      l_run[reg] = l_run[reg] * alpha + rs;
      m_run[reg] = mnew;
#pragma unroll
      for (int nc = 0; nc < 4; nc++) o_acc[nc][reg] *= alpha;
    }

    // ---- P (C layout) -> bf16 A-frag via per-wave LDS (wave-order safe)
#pragma unroll
    for (int nc = 0; nc < 4; nc++) {
      int jl = nc * 16 + ml;
      int kc = nc >> 1, qdj = (jl >> 3) & 3, jj = ml & 7;
#pragma unroll
      for (int reg = 0; reg < 4; reg++) {
        int rowl = quad * 4 + reg;
        pt[w][(kc * 64 + qdj * 16 + rowl) * 8 + jj] = (short)f2b(pv_[nc][reg]);
      }
    }
    short8 pf[2];
    pf[0] = *reinterpret_cast<const short8*>(pt[w] + (0 * 64 + lane) * 8);
    pf[1] = *reinterpret_cast<const short8*>(pt[w] + (1 * 64 + lane) * 8);

    // ---- PV: V B-frags from LDS (k = kc*32 + quad*8 + e)
#pragma unroll
    for (int ncd = 0; ncd < 4; ncd++)
#pragma unroll
      for (int kc = 0; kc < 2; kc++) {
        short8 vf = *reinterpret_cast<const short8*>(vb + ((kc * 4 + ncd) * 64 + lane) * 8);
        o_acc[ncd] = __builtin_amdgcn_mfma_f32_16x16x32_bf16(pf[kc], vf, o_acc[ncd], 0, 0, 0);
      }
  }

  // ---- write unnormalized partials.
#pragma unroll
  for (int reg = 0; reg < 4; reg++) {
    int ig = ig0 + quad * 4 + reg;
    size_t ridx = (s < 2) ? ((size_t)(s * 512 + ig) * 64 + bh)
                          : ((size_t)65536 + (size_t)(ig - 256) * 64 + bh);
    if (ml == 0) { pm[ridx] = m_run[reg]; pl[ridx] = l_run[reg]; }
#pragma unroll
    for (int ncd = 0; ncd < 4; ncd++)
      po[ridx * 64 + ncd * 16 + ml] = o_acc[ncd][reg];
  }
}

// ---------------------------------------------------------------------------
// Merge the (2 or 3) j-segments; write av in PACKED layout for the proj GEMM.
// One thread per 8 consecutive d (short8 store).
// ---------------------------------------------------------------------------
__global__ __launch_bounds__(256)
void combine(const float* __restrict__ po, const float* __restrict__ pm,
             const float* __restrict__ pl, u16* __restrict__ av) {
  int t = blockIdx.x * 256 + threadIdx.x;    // 262,144 total
  int r0 = t >> 3, d8 = (t & 7) * 8;         // r0 = ig*64 + b*16 + h
  int ig = r0 >> 6, b = (r0 >> 4) & 3, h = r0 & 15;
  float m1 = pm[r0], m2 = pm[32768 + r0];
  float l1 = pl[r0], l2 = pl[32768 + r0];
  const f32x4* p1 = reinterpret_cast<const f32x4*>(po + (size_t)r0 * 64 + d8);
  const f32x4* p2 = reinterpret_cast<const f32x4*>(po + ((size_t)32768 + r0) * 64 + d8);
  f32x4 o1a = p1[0], o1b = p1[1], o2a = p2[0], o2b = p2[1];
  float m = fmaxf(m1, m2);
  const bool h3 = ig >= 256;                 // slot 2 exists only for it>=4
  int r2 = r0 + 49152;
  float m3 = -1e30f, l3 = 0.f;
  f32x4 o3a = {0.f, 0.f, 0.f, 0.f}, o3b = {0.f, 0.f, 0.f, 0.f};
  if (h3) {
    m3 = pm[r2]; l3 = pl[r2];
    const f32x4* p3 = reinterpret_cast<const f32x4*>(po + (size_t)r2 * 64 + d8);
    o3a = p3[0]; o3b = p3[1];
    m = fmaxf(m, m3);
  }
  float a1 = __expf(m1 - m), a2 = __expf(m2 - m);
  float a3 = h3 ? __expf(m3 - m) : 0.f;
  float l = l1 * a1 + l2 * a2 + l3 * a3;
  short8 r;
#pragma unroll
  for (int e = 0; e < 4; e++) {
    r[e]     = (short)f2b((o1a[e] * a1 + o2a[e] * a2 + o3a[e] * a3) / l);
    r[e + 4] = (short)f2b((o1b[e] * a1 + o2b[e] * a2 + o3b[e] * a3) / l);
  }
  int row = ig * 4 + b, k = h * 64 + d8;
  *reinterpret_cast<short8*>(av + pidx8(row, k, 32)) = r;
}

// ---------------------------------------------------------------------------
extern "C" void kernel_launch(void* const* d_in, const int* in_sizes, int n_in,
                              void* d_out, int out_size, void* d_ws, size_t ws_size,
                              hipStream_t stream) {
  (void)in_sizes; (void)n_in; (void)out_size; (void)ws_size;

  const float* inputs  = (const float*)d_in[0];   // (512,4,1024)
  const float* pos_emb = (const float*)d_in[1];   // (1024,1,1024)
  const float* full_in = (const float*)d_in[2];   // (1024,4,1024)
  const float* u       = (const float*)d_in[3];   // (16,64)
  const float* v       = (const float*)d_in[4];   // (16,64)
  const float* W_kv    = (const float*)d_in[5];   // (1024,2048)
  const float* b_kv    = (const float*)d_in[6];   // (2048,)
  const float* W_q     = (const float*)d_in[7];   // (1024,1024)
  const float* b_q     = (const float*)d_in[8];
  const float* W_pos   = (const float*)d_in[9];   // (1024,1024)
  const float* b_pos   = (const float*)d_in[10];
  const float* W_proj  = (const float*)d_in[11];  // (1024,1024)
  const float* b_proj  = (const float*)d_in[12];
  // d_in[13] = mask (bool) — recomputed analytically (j > i + 512)
  float* out = (float*)d_out;

  char* ws = (char*)d_ws;
  u16* Kt2   = (u16*)(ws);                  //  8 MB: [4][16][16 tiles][4096] frag order
  u16* Vt2   = (u16*)(ws + ( 8u << 20));    //  8 MB: same shape, V frag order
  u16* qq    = (u16*)(ws + (16u << 20));    //  4 MB: 2048x1024 row-major
  u16* Rt    = (u16*)(ws + (20u << 20));    //  2 MB: [16 h][1024 rel][64 d]
  u16* av    = (u16*)(ws + (22u << 20));    //  4 MB: packed 2048x1024
  u16* WkvT  = (u16*)(ws + (26u << 20));    //  4 MB packed
  u16* WqT   = (u16*)(ws + (30u << 20));    //  2 MB packed
  u16* WposT = (u16*)(ws + (32u << 20));    //  2 MB packed
  u16* WprojT= (u16*)(ws + (34u << 20));    //  2 MB packed
  u16* fibf  = (u16*)(ws + (36u << 20));    //  8 MB packed (dead after gemm3)
  u16* inbf  = (u16*)(ws + (44u << 20));    //  4 MB packed (dead after gemm3)
  u16* pebf  = (u16*)(ws + (48u << 20));    //  2 MB packed (dead after gemm3)
  float* po  = (float*)(ws + (36u << 20));  // 20 MB partial O (slots 0/1/2; overlays the above)
  float* pm  = (float*)(ws + (56u << 20));  // 320 KB partial m (81920 floats)
  float* pl  = (float*)(ws + (57u << 20));  // 320 KB partial l

  // --- precompute (converts + weight transposes, one dispatch)
  hipLaunchKernelGGL(prep, dim3(5632), dim3(256), 0, stream,
                     full_in, inputs, pos_emb, fibf, inbf, pebf,
                     W_kv, W_q, W_pos, W_proj, WkvT, WqT, WposT, WprojT);

  // --- kv + q + r GEMMs, one dispatch (704 blocks)
  hipLaunchKernelGGL(gemm3, dim3(704), dim3(256), 0, stream,
                     fibf, WkvT, b_kv, Kt2, Vt2,
                     inbf, WqT, b_q, qq,
                     pebf, WposT, b_pos, Rt);

  // --- balanced split-j fused attention + 3-way combine
  hipLaunchKernelGGL(flash_xl, dim3(20, 4, 16), dim3(256), 0, stream,
                     qq, Kt2, Vt2, Rt, u, v, po, pm, pl);
  hipLaunchKernelGGL(combine, dim3(1024), dim3(256), 0, stream, po, pm, pl, av);

  // --- output projection
  hipLaunchKernelGGL(gemm_proj, dim3(8, 16), dim3(256), 0, stream,
                     av, WprojT, b_proj, out);
}

// Round 6
// 223.111 us; speedup vs baseline: 1.1701x; 1.0375x over previous
//
#include <hip/hip_runtime.h>

// AttentionXL (TransformerXL relative attention), MI355X gfx950.
// fp32 I/O. prep (convert+transpose, packed operands) -> gemm3 (kv+q+r) ->
// split-j flash -> combine (packed av) -> proj GEMM.
// Round 17: flash schedule reverted to round-0's 16 blocks/bh (A/B showed
// balanced 20-block was -5us WORSE: per-block prologue cost > balance gain;
// flash is per-tile-critical-path bound, not parallelism bound). One isolated
// body change: row-sum via ones-MFMA (2 MFMAs off the pf frag, concurrent
// with PV) replaces the 16-bpermute sum butterfly on the serial chain.

typedef unsigned short u16;
typedef short short8 __attribute__((ext_vector_type(8)));
typedef float f32x4 __attribute__((ext_vector_type(4)));

#define BSZ 4
#define PREV 512

__device__ __forceinline__ float b2f(u16 u) {
  union { unsigned int i; float f; } x; x.i = ((unsigned int)u) << 16; return x.f;
}
__device__ __forceinline__ u16 f2b(float f) {
  union { float f; unsigned int i; } x; x.f = f;
  unsigned int u = x.i;
  return (u16)((u + 0x7fffu + ((u >> 16) & 1u)) >> 16);
}
__device__ __forceinline__ void storeC(u16* C, size_t idx, float v) { C[idx] = f2b(v); }
__device__ __forceinline__ void storeC(float* C, size_t idx, float v) { C[idx] = v; }

// async 16B/lane global->LDS DMA; lds dest = wave-uniform base + lane*16
__device__ __forceinline__ void load_lds16(const u16* g, void* l) {
  __builtin_amdgcn_global_load_lds(
      (const __attribute__((address_space(1))) unsigned int*)g,
      (__attribute__((address_space(3))) unsigned int*)l, 16, 0, 0);
}

// Packed operand layout: matrix [R][K] tiled into 16x32 chunks of 512 u16.
// chunk = (row/16)*(K/32) + k/32; within-chunk = frag order
// [quad=(k>>3)&3][ml=row&15][e=k&7] -> a wave's lane*16B linear read of one
// chunk IS the MFMA A/B fragment layout. k must be 8-aligned here.
__device__ __forceinline__ size_t pidx8(int row, int k, int K32) {
  return (((size_t)((row >> 4) * K32 + (k >> 5))) << 9) +
         (((k >> 3) & 3) << 7) + ((row & 15) << 3);
}

// ---------------------------------------------------------------------------
// prep: 3 fp32->bf16 converts into PACKED layout (blocks 0..3583) + 4 weight
// transposes (fp32 W[K x N] -> packed bf16 WT) (blocks 3584..5631).
// ---------------------------------------------------------------------------
__global__ __launch_bounds__(256)
void prep(const float* __restrict__ s0, const float* __restrict__ s1,
          const float* __restrict__ s2, u16* __restrict__ d0,
          u16* __restrict__ d1, u16* __restrict__ d2,
          const float* __restrict__ W0, const float* __restrict__ W1,
          const float* __restrict__ W2, const float* __restrict__ W3,
          u16* __restrict__ T0, u16* __restrict__ T1,
          u16* __restrict__ T2, u16* __restrict__ T3) {
  __shared__ u16 ld[64 * 66];
  const int bxg = blockIdx.x;
  if (bxg < 3584) {
    // --- convert part: src row-major [R][1024], dst packed
    const float* s; u16* d; size_t base;
    if (bxg < 2048)      { s = s0; d = d0; base = (size_t)bxg * 2048; }
    else if (bxg < 3072) { s = s1; d = d1; base = (size_t)(bxg - 2048) * 2048; }
    else                 { s = s2; d = d2; base = (size_t)(bxg - 3072) * 2048; }
    size_t i = base + (size_t)threadIdx.x * 8;
    const f32x4* p = reinterpret_cast<const f32x4*>(s + i);
    f32x4 a = p[0], b = p[1];
    short8 r;
#pragma unroll
    for (int e = 0; e < 4; e++) { r[e] = (short)f2b(a[e]); r[e + 4] = (short)f2b(b[e]); }
    int row = (int)(i >> 10), k = (int)(i & 1023);
    *reinterpret_cast<short8*>(d + pidx8(row, k, 32)) = r;
    return;
  }
  // --- transpose part: W[K x N] -> packed WT (rows = n, cols = k, K=1024)
  const int l = bxg - 3584;
  const int z = l >> 9;
  const int rem = l & 511;
  const int bx = rem & 31, by = rem >> 5;
  const float* W; u16* T; int N;
  if (z == 0)      { W = W0; T = T0; N = 2048; }
  else if (z == 1) { W = W1; T = T1; N = 1024; }
  else if (z == 2) { W = W2; T = T2; N = 1024; }
  else             { W = W3; T = T3; N = 1024; }
  const int n0 = bx * 64, k0 = by * 64;
  if (n0 >= N) return;

  const int tid = threadIdx.x;
#pragma unroll
  for (int rep = 0; rep < 16; rep++) {
    int idx = tid + 256 * rep;
    int kk = idx >> 6, nn = idx & 63;
    ld[kk * 66 + nn] = f2b(W[(size_t)(k0 + kk) * N + n0 + nn]);
  }
  __syncthreads();
#pragma unroll
  for (int rep = 0; rep < 2; rep++) {
    int idx = tid + 256 * rep;           // 0..511
    int nn = idx >> 3, k8 = (idx & 7) * 8;
    short8 r;
#pragma unroll
    for (int e = 0; e < 8; e++) r[e] = (short)ld[(k8 + e) * 66 + nn];
    *reinterpret_cast<short8*>(T + pidx8(n0 + nn, k0 + k8, 32)) = r;
  }
}

// ---------------------------------------------------------------------------
// GEMM core: C = A @ BT^T + bias, A/BT in PACKED chunk layout. 128x128 tile,
// BK=64, single-buffer. Staging = contiguous-1KB global_load_lds; ds_read
// frag reads are lane-linear (0 bank conflicts).
// MODE 0: row-major C. MODE 1 (kv): Kt2/Vt2 frag-tile order. MODE 2: Rt.
// ---------------------------------------------------------------------------
template <typename OT, int MODE>
__device__ __forceinline__ void gemm_core(
    short* __restrict__ at, short* __restrict__ bt,
    const u16* __restrict__ A, const u16* __restrict__ BT,
    const float* __restrict__ bias, OT* __restrict__ C, u16* __restrict__ C2,
    int N, int K, int bx, int by)
{
  const int tid = threadIdx.x;
  const int lane = tid & 63, w = tid >> 6;
  const int wr = w >> 1, wc = w & 1;
  const int quad = lane >> 4, ml = lane & 15;
  const int row0 = by * 128, col0 = bx * 128;
  const int K32 = K >> 5;

  f32x4 acc[4][4];
  const f32x4 fzero = {0.f, 0.f, 0.f, 0.f};
#pragma unroll
  for (int i = 0; i < 4; i++)
#pragma unroll
    for (int j = 0; j < 4; j++) acc[i][j] = fzero;

  for (int k0 = 0; k0 < K; k0 += 64) {
    __syncthreads();  // previous tile fully consumed
#pragma unroll
    for (int i = 0; i < 4; i++) {
      int c = 4 * w + i;                 // chunk index 0..15
      int mc = c >> 1, kc = c & 1;
      size_t ca = ((size_t)(((row0 >> 4) + mc) * K32 + (k0 >> 5) + kc)) << 9;
      size_t cb = ((size_t)(((col0 >> 4) + mc) * K32 + (k0 >> 5) + kc)) << 9;
      load_lds16(A + ca + lane * 8, (void*)(at + c * 512));
      load_lds16(BT + cb + lane * 8, (void*)(bt + c * 512));
    }
    __syncthreads();  // drains vmcnt; staging visible

    short8 af[4][2], bf[4][2];
#pragma unroll
    for (int mc = 0; mc < 4; mc++)
#pragma unroll
      for (int kc = 0; kc < 2; kc++)
        af[mc][kc] = *reinterpret_cast<const short8*>(at + ((((wr * 4 + mc) * 2 + kc) * 64) + lane) * 8);
#pragma unroll
    for (int nc = 0; nc < 4; nc++)
#pragma unroll
      for (int kc = 0; kc < 2; kc++)
        bf[nc][kc] = *reinterpret_cast<const short8*>(bt + ((((wc * 4 + nc) * 2 + kc) * 64) + lane) * 8);

#pragma unroll
    for (int mc = 0; mc < 4; mc++)
#pragma unroll
      for (int nc = 0; nc < 4; nc++)
#pragma unroll
        for (int kc = 0; kc < 2; kc++)
          acc[mc][nc] = __builtin_amdgcn_mfma_f32_16x16x32_bf16(af[mc][kc], bf[nc][kc], acc[mc][nc], 0, 0, 0);
  }

#pragma unroll
  for (int nc = 0; nc < 4; nc++) {
    int col = col0 + wc * 64 + nc * 16 + ml;
    float bv = bias[col];
#pragma unroll
    for (int mc = 0; mc < 4; mc++) {
#pragma unroll
      for (int reg = 0; reg < 4; reg++) {
        int row = row0 + wr * 64 + mc * 16 + quad * 4 + reg;
        float val = acc[mc][nc][reg] + bv;
        if constexpr (MODE == 0) {
          storeC(C, (size_t)row * N + col, val);
        } else if constexpr (MODE == 1) {
          int j = row >> 2, bb = row & 3;
          int tile = j >> 6, jl = j & 63;
          if (col < 1024) {  // K half: frag (n=j, k=d)
            int h = col >> 6, d = col & 63;
            int ncj = jl >> 4, nlj = jl & 15, kcd = d >> 5, qdd = (d >> 3) & 3, jjd = d & 7;
            C[((size_t)(bb * 16 + h) * 16 + tile) * 4096 +
              ((ncj * 2 + kcd) * 64 + qdd * 16 + nlj) * 8 + jjd] = f2b(val);
          } else {           // V half: frag (n=d, k=j)
            int c2 = col - 1024;
            int h = c2 >> 6, d = c2 & 63;
            int ncd = d >> 4, nld = d & 15, kcj = jl >> 5, qdj = (jl >> 3) & 3, jjj = jl & 7;
            C2[((size_t)(bb * 16 + h) * 16 + tile) * 4096 +
               ((kcj * 4 + ncd) * 64 + qdj * 16 + nld) * 8 + jjj] = f2b(val);
          }
        } else {             // MODE 2: Rt[h][rel][d]
          int h = col >> 6, d = col & 63;
          C[((size_t)h * 1024 + row) * 64 + d] = f2b(val);
        }
      }
    }
  }
}

// ---------------------------------------------------------------------------
// gemm3: kv (512 blocks) + q (128) + r (64) batched in one 704-block dispatch.
// ---------------------------------------------------------------------------
__global__ __launch_bounds__(256, 2)
void gemm3(const u16* __restrict__ fibf, const u16* __restrict__ WkvT,
           const float* __restrict__ b_kv, u16* __restrict__ Kt2, u16* __restrict__ Vt2,
           const u16* __restrict__ inbf, const u16* __restrict__ WqT,
           const float* __restrict__ b_q, u16* __restrict__ qq,
           const u16* __restrict__ pebf, const u16* __restrict__ WposT,
           const float* __restrict__ b_pos, u16* __restrict__ Rt)
{
  __shared__ __align__(16) short at[8192];
  __shared__ __align__(16) short bt[8192];
  const int id = blockIdx.x;
  if (id < 512) {
    gemm_core<u16, 1>(at, bt, fibf, WkvT, b_kv, Kt2, Vt2, 2048, 1024, id & 15, id >> 4);
  } else if (id < 640) {
    const int l = id - 512;
    gemm_core<u16, 0>(at, bt, inbf, WqT, b_q, qq, (u16*)nullptr, 1024, 1024, l & 7, l >> 3);
  } else {
    const int l = id - 640;
    gemm_core<u16, 2>(at, bt, pebf, WposT, b_pos, Rt, (u16*)nullptr, 1024, 1024, l & 7, l >> 3);
  }
}

__global__ __launch_bounds__(256, 2)
void gemm_proj(const u16* __restrict__ A, const u16* __restrict__ BT,
               const float* __restrict__ bias, float* __restrict__ C)
{
  __shared__ __align__(16) short at[8192];
  __shared__ __align__(16) short bt[8192];
  gemm_core<float, 0>(at, bt, A, BT, bias, C, (u16*)nullptr, 1024, 1024,
                      blockIdx.x, blockIdx.y);
}

// ---------------------------------------------------------------------------
// Split-j fused flash-XL, round-0 schedule (16 blocks/bh, longest-first,
// 4 blocks/CU all-resident) + ones-MFMA row-sum (replaces sum butterfly).
// ---------------------------------------------------------------------------
__global__ __launch_bounds__(256, 4)
void flash_xl(const u16* __restrict__ q, const u16* __restrict__ Kt2,
              const u16* __restrict__ Vt2, const u16* __restrict__ Rt,
              const float* __restrict__ u, const float* __restrict__ v,
              float* __restrict__ po, float* __restrict__ pm,
              float* __restrict__ pl)
{
  __shared__ __align__(16) short kb[4096];
  __shared__ __align__(16) short vb[4096];
  __shared__ __align__(16) short pt[4][1024];

  const int tid = threadIdx.x, lane = tid & 63, w = tid >> 6;
  const int quad = lane >> 4, ml = lane & 15;
  const int x = blockIdx.x;
  const int it = 7 - (x >> 1), s = x & 1;     // longest i-tiles dispatched first
  const int nt = it + 9;                      // total tiles covering j <= i0+63+512
  const int nt0 = (nt + 1) >> 1;              // seg0 tile count
  const int ts = s ? nt0 : 0, te = s ? nt : nt0;

  const int b = blockIdx.y, h = blockIdx.z;
  const int bh = b * 16 + h;
  const int i0 = it * 64, ig0 = i0 + w * 16;

  const u16* Kbase = Kt2 + ((size_t)(b * 16 + h) * 16) * 4096;
  const u16* Vbase = Vt2 + ((size_t)(b * 16 + h) * 16) * 4096;
  const u16* Rp = Rt + (size_t)h * 65536;

  // Q fragments, pre-scaled by 1/8: rows ig0+ml, k = kc*32+quad*8+e
  short8 qu[2], qvf[2];
  {
    int ig = ig0 + ml;
#pragma unroll
    for (int kc = 0; kc < 2; kc++) {
      int dbase = kc * 32 + quad * 8;
      short8 qq = *reinterpret_cast<const short8*>(q + ((size_t)ig * BSZ + b) * 1024 + h * 64 + dbase);
      const f32x4* up = reinterpret_cast<const f32x4*>(u + h * 64 + dbase);
      const f32x4* vp = reinterpret_cast<const f32x4*>(v + h * 64 + dbase);
      f32x4 u0 = up[0], u1 = up[1], v0 = vp[0], v1 = vp[1];
#pragma unroll
      for (int e = 0; e < 8; e++) {
        float qf = b2f((u16)qq[e]);
        float uu = (e < 4) ? u0[e] : u1[e - 4];
        float vv = (e < 4) ? v0[e] : v1[e - 4];
        qu[kc][e]  = (short)f2b((qf + uu) * 0.125f);
        qvf[kc][e] = (short)f2b((qf + vv) * 0.125f);
      }
    }
  }

  // all-ones bf16 B-fragment for the row-sum MFMA
  short8 kones;
#pragma unroll
  for (int e = 0; e < 8; e++) kones[e] = (short)0x3F80;

  const f32x4 fzero = {0.f, 0.f, 0.f, 0.f};
  f32x4 o_acc[4];
#pragma unroll
  for (int i = 0; i < 4; i++) o_acc[i] = fzero;
  float m_run[4], l_run[4];
#pragma unroll
  for (int i = 0; i < 4; i++) { m_run[i] = -1e30f; l_run[i] = 0.f; }

  // ---- prologue: prefetch tile ts's identity chunks into registers
  short8 pk0, pk1, pv0, pv1;
  {
    const u16* kg = Kbase + (size_t)ts * 4096;
    const u16* vg = Vbase + (size_t)ts * 4096;
    pk0 = *reinterpret_cast<const short8*>(kg + tid * 8);
    pk1 = *reinterpret_cast<const short8*>(kg + 2048 + tid * 8);
    pv0 = *reinterpret_cast<const short8*>(vg + tid * 8);
    pv1 = *reinterpret_cast<const short8*>(vg + 2048 + tid * 8);
  }

  for (int t = ts; t < te; t++) {
    const int j0 = t * 64;
    __syncthreads();  // previous tile fully consumed
    *reinterpret_cast<short8*>(kb + tid * 8) = pk0;
    *reinterpret_cast<short8*>(kb + 2048 + tid * 8) = pk1;
    *reinterpret_cast<short8*>(vb + tid * 8) = pv0;
    *reinterpret_cast<short8*>(vb + 2048 + tid * 8) = pv1;
    __syncthreads();  // staging visible

    // ---- issue next tile's prefetch (latency hidden behind this tile's body)
    if (t + 1 < te) {
      const u16* kg = Kbase + (size_t)(t + 1) * 4096;
      const u16* vg = Vbase + (size_t)(t + 1) * 4096;
      pk0 = *reinterpret_cast<const short8*>(kg + tid * 8);
      pk1 = *reinterpret_cast<const short8*>(kg + 2048 + tid * 8);
      pv0 = *reinterpret_cast<const short8*>(vg + tid * 8);
      pv1 = *reinterpret_cast<const short8*>(vg + 2048 + tid * 8);
    }

    // ---- content scores: K B-frags from LDS
    f32x4 sc[4];
#pragma unroll
    for (int nc = 0; nc < 4; nc++) {
      sc[nc] = fzero;
#pragma unroll
      for (int kc = 0; kc < 2; kc++) {
        short8 kf = *reinterpret_cast<const short8*>(kb + ((nc * 2 + kc) * 64 + lane) * 8);
        sc[nc] = __builtin_amdgcn_mfma_f32_16x16x32_bf16(qu[kc], kf, sc[nc], 0, 0, 0);
      }
    }
    // ---- position strip: R B-frags direct from global (dense 1KB windows)
    const int relstart = j0 - ig0 + 496;  // >= 0
    f32x4 p2[5];
#pragma unroll
    for (int c = 0; c < 5; c++) {
      p2[c] = fzero;
      int rel = relstart + c * 16 + ml;
      if (rel > 1023) rel = 1023;  // clamped rows are masked below
      const u16* rp = Rp + (size_t)rel * 64 + quad * 8;
#pragma unroll
      for (int kc = 0; kc < 2; kc++) {
        short8 rf = *reinterpret_cast<const short8*>(rp + kc * 32);
        p2[c] = __builtin_amdgcn_mfma_f32_16x16x32_bf16(qvf[kc], rf, p2[c], 0, 0, 0);
      }
    }

    // ---- rel-shift gather (quad-local shuffles) + mask + online softmax
    const bool anymask = (j0 + 63) > (ig0 + PREV);
    float pv_[4][4];
    float tmax[4] = {-1e30f, -1e30f, -1e30f, -1e30f};
#pragma unroll
    for (int reg = 0; reg < 4; reg++) {
      int rowl = quad * 4 + reg;
      int src = quad * 16 + ((ml - rowl - 1) & 15);
      bool hi = ml > rowl;
      float sh[5];
#pragma unroll
      for (int c = 0; c < 5; c++) sh[c] = __shfl(p2[c][reg], src, 64);
#pragma unroll
      for (int nc = 0; nc < 4; nc++) {
        float sv = sc[nc][reg] + (hi ? sh[nc + 1] : sh[nc]);
        if (anymask) {
          int jg = j0 + nc * 16 + ml;
          if (jg > ig0 + rowl + PREV) sv = -1e30f;
        }
        pv_[nc][reg] = sv;
        tmax[reg] = fmaxf(tmax[reg], sv);
      }
    }
    // ---- row-max butterfly + exp; l-sum deferred to the ones-MFMA below
#pragma unroll
    for (int reg = 0; reg < 4; reg++) {
      float tm = tmax[reg];
#pragma unroll
      for (int off = 1; off < 16; off <<= 1) tm = fmaxf(tm, __shfl_xor(tm, off, 64));
      float mnew = fmaxf(m_run[reg], tm);
      float alpha = __expf(m_run[reg] - mnew);
#pragma unroll
      for (int nc = 0; nc < 4; nc++)
        pv_[nc][reg] = __expf(pv_[nc][reg] - mnew);
      l_run[reg] *= alpha;
      m_run[reg] = mnew;
#pragma unroll
      for (int nc = 0; nc < 4; nc++) o_acc[nc][reg] *= alpha;
    }

    // ---- P (C layout) -> bf16 A-frag via per-wave LDS (wave-order safe)
#pragma unroll
    for (int nc = 0; nc < 4; nc++) {
      int jl = nc * 16 + ml;
      int kc = nc >> 1, qdj = (jl >> 3) & 3, jj = ml & 7;
#pragma unroll
      for (int reg = 0; reg < 4; reg++) {
        int rowl = quad * 4 + reg;
        pt[w][(kc * 64 + qdj * 16 + rowl) * 8 + jj] = (short)f2b(pv_[nc][reg]);
      }
    }
    short8 pf[2];
    pf[0] = *reinterpret_cast<const short8*>(pt[w] + (0 * 64 + lane) * 8);
    pf[1] = *reinterpret_cast<const short8*>(pt[w] + (1 * 64 + lane) * 8);

    // ---- row-sum of P via ones-MFMA (concurrent with PV on the MFMA pipe);
    //      l is the sum of bf16 P, consistent with the bf16-P numerator.
    f32x4 lsum = fzero;
    lsum = __builtin_amdgcn_mfma_f32_16x16x32_bf16(pf[0], kones, lsum, 0, 0, 0);
    lsum = __builtin_amdgcn_mfma_f32_16x16x32_bf16(pf[1], kones, lsum, 0, 0, 0);

    // ---- PV: V B-frags from LDS (k = kc*32 + quad*8 + e)
#pragma unroll
    for (int ncd = 0; ncd < 4; ncd++)
#pragma unroll
      for (int kc = 0; kc < 2; kc++) {
        short8 vf = *reinterpret_cast<const short8*>(vb + ((kc * 4 + ncd) * 64 + lane) * 8);
        o_acc[ncd] = __builtin_amdgcn_mfma_f32_16x16x32_bf16(pf[kc], vf, o_acc[ncd], 0, 0, 0);
      }
#pragma unroll
    for (int reg = 0; reg < 4; reg++) l_run[reg] += lsum[reg];
  }

  // ---- write unnormalized partials: ridx = (s*512+ig)*64 + bh
#pragma unroll
  for (int reg = 0; reg < 4; reg++) {
    int ig = ig0 + quad * 4 + reg;
    size_t ridx = (size_t)(s * 512 + ig) * 64 + bh;
    if (ml == 0) { pm[ridx] = m_run[reg]; pl[ridx] = l_run[reg]; }
#pragma unroll
    for (int ncd = 0; ncd < 4; ncd++)
      po[ridx * 64 + ncd * 16 + ml] = o_acc[ncd][reg];
  }
}

// ---------------------------------------------------------------------------
// Merge the two j-segments; write av in PACKED layout for the proj GEMM.
// One thread per 8 consecutive d (short8 store).
// ---------------------------------------------------------------------------
__global__ __launch_bounds__(256)
void combine(const float* __restrict__ po, const float* __restrict__ pm,
             const float* __restrict__ pl, u16* __restrict__ av) {
  int t = blockIdx.x * 256 + threadIdx.x;    // 262,144 total
  int r0 = t >> 3, d8 = (t & 7) * 8;         // r0 = ig*64 + b*16 + h
  int ig = r0 >> 6, b = (r0 >> 4) & 3, h = r0 & 15;
  float m1 = pm[r0], m2 = pm[32768 + r0];
  float l1 = pl[r0], l2 = pl[32768 + r0];
  const f32x4* p1 = reinterpret_cast<const f32x4*>(po + (size_t)r0 * 64 + d8);
  const f32x4* p2 = reinterpret_cast<const f32x4*>(po + ((size_t)32768 + r0) * 64 + d8);
  f32x4 o1a = p1[0], o1b = p1[1], o2a = p2[0], o2b = p2[1];
  float m = fmaxf(m1, m2);
  float a1 = __expf(m1 - m), a2 = __expf(m2 - m);
  float l = l1 * a1 + l2 * a2;
  short8 r;
#pragma unroll
  for (int e = 0; e < 4; e++) {
    r[e]     = (short)f2b((o1a[e] * a1 + o2a[e] * a2) / l);
    r[e + 4] = (short)f2b((o1b[e] * a1 + o2b[e] * a2) / l);
  }
  int row = ig * 4 + b, k = h * 64 + d8;
  *reinterpret_cast<short8*>(av + pidx8(row, k, 32)) = r;
}

// ---------------------------------------------------------------------------
extern "C" void kernel_launch(void* const* d_in, const int* in_sizes, int n_in,
                              void* d_out, int out_size, void* d_ws, size_t ws_size,
                              hipStream_t stream) {
  (void)in_sizes; (void)n_in; (void)out_size; (void)ws_size;

  const float* inputs  = (const float*)d_in[0];   // (512,4,1024)
  const float* pos_emb = (const float*)d_in[1];   // (1024,1,1024)
  const float* full_in = (const float*)d_in[2];   // (1024,4,1024)
  const float* u       = (const float*)d_in[3];   // (16,64)
  const float* v       = (const float*)d_in[4];   // (16,64)
  const float* W_kv    = (const float*)d_in[5];   // (1024,2048)
  const float* b_kv    = (const float*)d_in[6];   // (2048,)
  const float* W_q     = (const float*)d_in[7];   // (1024,1024)
  const float* b_q     = (const float*)d_in[8];
  const float* W_pos   = (const float*)d_in[9];   // (1024,1024)
  const float* b_pos   = (const float*)d_in[10];
  const float* W_proj  = (const float*)d_in[11];  // (1024,1024)
  const float* b_proj  = (const float*)d_in[12];
  // d_in[13] = mask (bool) — recomputed analytically (j > i + 512)
  float* out = (float*)d_out;

  char* ws = (char*)d_ws;
  u16* Kt2   = (u16*)(ws);                  //  8 MB: [4][16][16 tiles][4096] frag order
  u16* Vt2   = (u16*)(ws + ( 8u << 20));    //  8 MB: same shape, V frag order
  u16* qq    = (u16*)(ws + (16u << 20));    //  4 MB: 2048x1024 row-major
  u16* Rt    = (u16*)(ws + (20u << 20));    //  2 MB: [16 h][1024 rel][64 d]
  u16* av    = (u16*)(ws + (22u << 20));    //  4 MB: packed 2048x1024
  u16* WkvT  = (u16*)(ws + (26u << 20));    //  4 MB packed
  u16* WqT   = (u16*)(ws + (30u << 20));    //  2 MB packed
  u16* WposT = (u16*)(ws + (32u << 20));    //  2 MB packed
  u16* WprojT= (u16*)(ws + (34u << 20));    //  2 MB packed
  u16* fibf  = (u16*)(ws + (36u << 20));    //  8 MB packed (dead after gemm3)
  u16* inbf  = (u16*)(ws + (44u << 20));    //  4 MB packed (dead after gemm3)
  u16* pebf  = (u16*)(ws + (48u << 20));    //  2 MB packed (dead after gemm3)
  float* po  = (float*)(ws + (36u << 20));  // 16 MB partial O (2 slots; overlays the above)
  float* pm  = (float*)(ws + (52u << 20));  // 256 KB partial m (65536 floats)
  float* pl  = (float*)(ws + (52u << 20) + (256u << 10));  // 256 KB partial l

  // --- precompute (converts + weight transposes, one dispatch)
  hipLaunchKernelGGL(prep, dim3(5632), dim3(256), 0, stream,
                     full_in, inputs, pos_emb, fibf, inbf, pebf,
                     W_kv, W_q, W_pos, W_proj, WkvT, WqT, WposT, WprojT);

  // --- kv + q + r GEMMs, one dispatch (704 blocks)
  hipLaunchKernelGGL(gemm3, dim3(704), dim3(256), 0, stream,
                     fibf, WkvT, b_kv, Kt2, Vt2,
                     inbf, WqT, b_q, qq,
                     pebf, WposT, b_pos, Rt);

  // --- split-j fused attention + combine
  hipLaunchKernelGGL(flash_xl, dim3(16, 4, 16), dim3(256), 0, stream,
                     qq, Kt2, Vt2, Rt, u, v, po, pm, pl);
  hipLaunchKernelGGL(combine, dim3(1024), dim3(256), 0, stream, po, pm, pl, av);

  // --- output projection
  hipLaunchKernelGGL(gemm_proj, dim3(8, 16), dim3(256), 0, stream,
                     av, WprojT, b_proj, out);
}